// Round 10
// baseline (66.320 us; speedup 1.0000x reference)
//
#include <hip/hip_runtime.h>
#include <stdint.h>

#define B_ 512
#define M_ 32
#define D_ 2048

typedef float fvec4 __attribute__((ext_vector_type(4)));

// One block per batch, 1024 threads.
// Phase A (row-major): thread (m,t) sums its 16 float4s of row m -> butterfly.
// Phase B: one wave computes the 32x32 decay matvec -> coefs in LDS.
// Phase C (position-major): thread (h,p) loads its 3 w-float4s ONCE and streams
// 16 rows: re-load x[row][p] (L3-resident after phase A), FMA, nontemporal store.
// x is NOT held across the barrier (compiler refuses anyway: rounds 2/5/8/9);
// the position-major remap cuts phase-C w traffic 16x (48B vs 768B per thread).
__global__ __launch_bounds__(1024) void ephaptic_fused(const float* __restrict__ x,
                                                       const float* __restrict__ w,
                                                       float* __restrict__ out) {
    const int b = blockIdx.x;
    const int tid = threadIdx.x;

    __shared__ float sT[M_], sF[M_], sL[M_];
    __shared__ fvec4 sC[M_];

    const float* xb = x + (size_t)b * M_ * D_;
    float* ob = out + (size_t)b * M_ * D_;

    // ---- Phase A: row-major reduction. thread = (m, t)
    {
        const int m = tid >> 5;
        const int t = tid & 31;
        const fvec4* row = (const fvec4*)(xb + (size_t)m * D_);
        float sum = 0.f, first = 0.f, last = 0.f;
#pragma unroll
        for (int q = 0; q < 16; ++q) {
            const fvec4 v = row[t + 32 * q];
            sum += (v.x + v.y) + (v.z + v.w);
            if (q == 0)  first = v.x;   // x[m][0]    (lane t==0)
            if (q == 15) last  = v.w;   // x[m][2047] (lane t==31)
        }
#pragma unroll
        for (int off = 16; off > 0; off >>= 1)
            sum += __shfl_xor(sum, off, 64);
        if (t == 0)  { sT[m] = sum; sF[m] = first; }
        if (t == 31) { sL[m] = last; }
    }
    __syncthreads();

    // ---- Phase B: 32x32 decay matvec -> per-row coefficients (one wave).
    if (tid < M_) {
        const int i = tid;
        float r0 = 0.f, r1 = 0.f, r2 = 0.f;
        for (int j = 0; j < M_; ++j) {
            if (j == i) continue;
            const float dij = __expf(-0.5f * fabsf((float)(i - j)));
            const float T = sT[j];
            r0 += dij * (T - sL[j]);   // tap k=0: drop last element
            r1 += dij * T;             // tap k=1
            r2 += dij * (T - sF[j]);   // tap k=2: drop first element
        }
        const float s = 0.1f / (float)D_;
        sC[i] = (fvec4){r0 * s, r1 * s, r2 * s, 0.f};
    }
    __syncthreads();

    // ---- Phase C: position-major stream. thread = (h, p); w loaded once.
    {
        const int p = tid & 511;        // float4 position in the row
        const int h = tid >> 9;         // half: rows h*16 .. h*16+15
        const fvec4* wf = (const fvec4*)w;
        const fvec4 w0 = wf[p * 3 + 0];
        const fvec4 w1 = wf[p * 3 + 1];
        const fvec4 w2 = wf[p * 3 + 2];
#pragma unroll 4
        for (int r = 0; r < 16; ++r) {
            const int row = h * 16 + r;
            const fvec4 c = sC[row];    // LDS broadcast
            const fvec4 xv = ((const fvec4*)(xb + (size_t)row * D_))[p];
            fvec4 o;
            o.x = xv.x + c.x * w0.x + c.y * w0.y + c.z * w0.z;
            o.y = xv.y + c.x * w0.w + c.y * w1.x + c.z * w1.y;
            o.z = xv.z + c.x * w1.z + c.y * w1.w + c.z * w2.x;
            o.w = xv.w + c.x * w2.y + c.y * w2.z + c.z * w2.w;
            // nontemporal: out is never re-read; keep L3 for x
            __builtin_nontemporal_store(o, ((fvec4*)(ob + (size_t)row * D_)) + p);
        }
    }
}

extern "C" void kernel_launch(void* const* d_in, const int* in_sizes, int n_in,
                              void* d_out, int out_size, void* d_ws, size_t ws_size,
                              hipStream_t stream) {
    const float* x = (const float*)d_in[0];
    const float* w = (const float*)d_in[1];
    float* out = (float*)d_out;
    ephaptic_fused<<<B_, 1024, 0, stream>>>(x, w, out);
}